// Round 8
// baseline (216.530 us; speedup 1.0000x reference)
//
#include <hip/hip_runtime.h>
#include <hip/hip_fp16.h>
#include <math.h>

#define N_NODES 40000
#define FEATD 128
#define EMB 64
#define N_EDGES 640000
#define CAP 64   // max in-degree bucket; Poisson(16) max over 40k nodes ~40

typedef unsigned short u16;
typedef __attribute__((ext_vector_type(8))) unsigned short u16x8;
typedef __attribute__((ext_vector_type(8))) _Float16 f16x8;
typedef __attribute__((ext_vector_type(4))) float f32x4;

__device__ __forceinline__ float h2f(u16 h) {
  __half hh;
  *(u16*)&hh = h;
  return __half2float(hh);
}
__device__ __forceinline__ u16 f2h(float f) {
  __half hh = __float2half(f);
  return *(u16*)&hh;
}

// ---- merged prep (x->fp16, W->fp16) + CSR-bucket fill, one launch ----
// wp layout (u16): w1l(16384) | w1r(16384) | w2l(8192) | w2r(8192)
__global__ __launch_bounds__(256) void prep_fill_kernel(
    const float* __restrict__ x, const float* __restrict__ W1l,
    const float* __restrict__ W1r, const float* __restrict__ W2l,
    const float* __restrict__ W2r, const int* __restrict__ src,
    const int* __restrict__ dst, u16* __restrict__ xh,
    u16* __restrict__ wp, int* __restrict__ deg, u16* __restrict__ bucket) {
  int bid = blockIdx.x;
  if (bid < 2500) {                        // x -> fp16, 8 elems/thread
    int i = bid * 256 + threadIdx.x;
    float4 v0 = *(const float4*)(&x[i * 8]);
    float4 v1 = *(const float4*)(&x[i * 8 + 4]);
    u16x8 o;
    o[0] = f2h(v0.x); o[1] = f2h(v0.y); o[2] = f2h(v0.z); o[3] = f2h(v0.w);
    o[4] = f2h(v1.x); o[5] = f2h(v1.y); o[6] = f2h(v1.z); o[7] = f2h(v1.w);
    *(u16x8*)(&xh[i * 8]) = o;
  } else if (bid < 2692) {                 // W -> fp16
    int i = (bid - 2500) * 256 + threadIdx.x;   // [0, 49152)
    const float* srcp;
    int off;
    if (i < 16384)      { srcp = W1l; off = i; }
    else if (i < 32768) { srcp = W1r; off = i - 16384; }
    else if (i < 40960) { srcp = W2l; off = i - 32768; }
    else                { srcp = W2r; off = i - 40960; }
    wp[i] = f2h(srcp[off]);
  } else {                                 // edge fill: 1 int atomic/edge
    int e = (bid - 2692) * 256 + threadIdx.x;
    if (e >= N_EDGES) return;
    int s = src[e];
    int d = dst[e];
    int pos = atomicAdd(&deg[d], 1);
    if (pos < CAP) bucket[d * CAP + pos] = (u16)s;
  }
}

// ---- fused: gather-mean (LDS) -> layer-1 MFMA -> h (LDS) -> layer-2 MFMA ----
// Per block: 64 nodes. W/X fragments read directly from global (L2-resident);
// LDS holds only agg[64][136] + h[64][136] (stride 136 u16: bank-spread rows).
__global__ __launch_bounds__(256) void gemm12_kernel(
    const u16* __restrict__ xh, const u16* __restrict__ wp,
    const float* __restrict__ b1v, const float* __restrict__ b2v,
    const int* __restrict__ deg, const u16* __restrict__ bucket,
    u16* __restrict__ Yh, u16* __restrict__ Zh) {
  const u16* w1l = wp;
  const u16* w1r = wp + 16384;
  const u16* w2l = wp + 32768;
  const u16* w2r = wp + 40960;

  __shared__ __align__(16) u16 sAgg[64][136];   // 17408 B
  __shared__ __align__(16) u16 sH[64][136];     // 17408 B

  const int tid = threadIdx.x;
  const int wv = tid >> 6;
  const int lane = tid & 63;
  const int li = lane & 15;
  const int q = lane >> 4;
  const int nbase = blockIdx.x * 64;

  // ---- integrated gather-mean: 4 lanes/node x 32 dims/lane ----
  {
    int n = tid >> 2;                     // 0..63
    int g = tid & 3;                      // dim group [g*32, g*32+32)
    int gn = nbase + n;
    int dgf = deg[gn];
    int dg = dgf < CAP ? dgf : CAP;
    float inv = 1.0f / fmaxf((float)dgf, 1.0f);
    const u16* bk = bucket + gn * CAP;
    float acc[32];
#pragma unroll
    for (int i = 0; i < 32; i++) acc[i] = 0.f;
    for (int d = 0; d < dg; d++) {
      const u16* row = &xh[(int)bk[d] * 128 + g * 32];
      u16x8 v0 = *(const u16x8*)(row);
      u16x8 v1 = *(const u16x8*)(row + 8);
      u16x8 v2 = *(const u16x8*)(row + 16);
      u16x8 v3 = *(const u16x8*)(row + 24);
#pragma unroll
      for (int i = 0; i < 8; i++) {
        acc[i]      += h2f(v0[i]);
        acc[8 + i]  += h2f(v1[i]);
        acc[16 + i] += h2f(v2[i]);
        acc[24 + i] += h2f(v3[i]);
      }
    }
#pragma unroll
    for (int c = 0; c < 4; c++) {
      u16x8 o;
#pragma unroll
      for (int i = 0; i < 8; i++) o[i] = f2h(acc[c * 8 + i] * inv);
      *(u16x8*)(&sAgg[n][g * 32 + c * 8]) = o;
    }
  }
  __syncthreads();

  // ---- phase 1: h = elu(Agg@W1l^T + b1 + X@W1r^T), barrier-free ----
  f32x4 acc1[8];
#pragma unroll
  for (int jt = 0; jt < 8; jt++) acc1[jt] = (f32x4){0.f, 0.f, 0.f, 0.f};

#pragma unroll
  for (int kc = 0; kc < 4; kc++) {
    f16x8 aF = *(const f16x8*)(&sAgg[wv * 16 + li][kc * 32 + q * 8]);
    f16x8 xF = *(const f16x8*)(&xh[(nbase + wv * 16 + li) * 128 + kc * 32 + q * 8]);
#pragma unroll
    for (int jt = 0; jt < 8; jt++) {
      f16x8 wlF = *(const f16x8*)(&w1l[(jt * 16 + li) * 128 + kc * 32 + q * 8]);
      f16x8 wrF = *(const f16x8*)(&w1r[(jt * 16 + li) * 128 + kc * 32 + q * 8]);
      acc1[jt] = __builtin_amdgcn_mfma_f32_16x16x32_f16(aF, wlF, acc1[jt], 0, 0, 0);
      acc1[jt] = __builtin_amdgcn_mfma_f32_16x16x32_f16(xF, wrF, acc1[jt], 0, 0, 0);
    }
  }

  // epilogue 1: bias + elu, h -> LDS fp16 (C/D layout: row = q*4+reg)
#pragma unroll
  for (int jt = 0; jt < 8; jt++) {
    int j = jt * 16 + li;
    float bb = b1v[j];
#pragma unroll
    for (int r = 0; r < 4; r++) {
      float v = acc1[jt][r] + bb;
      v = v > 0.f ? v : expm1f(v);
      sH[wv * 16 + q * 4 + r][j] = f2h(v);
    }
  }
  __syncthreads();

  // ---- phase 2: y = h@W2l^T, z = b2 + h@W2r^T ----
  f32x4 accY[4], accZ[4];
#pragma unroll
  for (int mt = 0; mt < 4; mt++) {
    accY[mt] = (f32x4){0.f, 0.f, 0.f, 0.f};
    accZ[mt] = (f32x4){0.f, 0.f, 0.f, 0.f};
  }
#pragma unroll
  for (int kc = 0; kc < 4; kc++) {
    f16x8 blF = *(const f16x8*)(&w2l[(wv * 16 + li) * 128 + kc * 32 + q * 8]);
    f16x8 brF = *(const f16x8*)(&w2r[(wv * 16 + li) * 128 + kc * 32 + q * 8]);
#pragma unroll
    for (int mt = 0; mt < 4; mt++) {
      f16x8 hF = *(const f16x8*)(&sH[mt * 16 + li][kc * 32 + q * 8]);
      accY[mt] = __builtin_amdgcn_mfma_f32_16x16x32_f16(hF, blF, accY[mt], 0, 0, 0);
      accZ[mt] = __builtin_amdgcn_mfma_f32_16x16x32_f16(hF, brF, accZ[mt], 0, 0, 0);
    }
  }

  // epilogue 2: y, z -> fp16
  {
    int j2 = wv * 16 + li;
    float bb = b2v[j2];
#pragma unroll
    for (int mt = 0; mt < 4; mt++) {
#pragma unroll
      for (int r = 0; r < 4; r++) {
        int node = nbase + mt * 16 + q * 4 + r;
        Yh[node * 64 + j2] = f2h(accY[mt][r]);
        Zh[node * 64 + j2] = f2h(accZ[mt][r] + bb);
      }
    }
  }
}

// ---- final: out = log_softmax(z + mean_j y_j), y/z fp16 ----
__global__ __launch_bounds__(256) void final_kernel(
    const u16* __restrict__ Y, const u16* __restrict__ Z,
    const int* __restrict__ deg, const u16* __restrict__ bucket,
    float* __restrict__ out) {
  int n = blockIdx.x * 4 + (threadIdx.x >> 6);
  int lane = threadIdx.x & 63;
  int g = lane >> 4;
  int li = lane & 15;
  int dgf = deg[n];
  int dg = dgf < CAP ? dgf : CAP;
  float inv = 1.0f / fmaxf((float)dgf, 1.0f);
  const u16* bk = bucket + n * CAP;
  float4 acc = {0.f, 0.f, 0.f, 0.f};
  for (int d = g; d < dg; d += 4) {
    ushort4 v = *(const ushort4*)(&Y[(int)bk[d] * 64 + li * 4]);
    acc.x += h2f(v.x); acc.y += h2f(v.y); acc.z += h2f(v.z); acc.w += h2f(v.w);
  }
  acc.x += __shfl_xor(acc.x, 16); acc.y += __shfl_xor(acc.y, 16);
  acc.z += __shfl_xor(acc.z, 16); acc.w += __shfl_xor(acc.w, 16);
  acc.x += __shfl_xor(acc.x, 32); acc.y += __shfl_xor(acc.y, 32);
  acc.z += __shfl_xor(acc.z, 32); acc.w += __shfl_xor(acc.w, 32);
  ushort4 zb4 = *(const ushort4*)(&Z[n * 64 + li * 4]);
  float4 v;
  v.x = h2f(zb4.x) + acc.x * inv; v.y = h2f(zb4.y) + acc.y * inv;
  v.z = h2f(zb4.z) + acc.z * inv; v.w = h2f(zb4.w) + acc.w * inv;
  float m = fmaxf(fmaxf(v.x, v.y), fmaxf(v.z, v.w));
  m = fmaxf(m, __shfl_xor(m, 1)); m = fmaxf(m, __shfl_xor(m, 2));
  m = fmaxf(m, __shfl_xor(m, 4)); m = fmaxf(m, __shfl_xor(m, 8));
  float s = __expf(v.x - m) + __expf(v.y - m) + __expf(v.z - m) + __expf(v.w - m);
  s += __shfl_xor(s, 1); s += __shfl_xor(s, 2);
  s += __shfl_xor(s, 4); s += __shfl_xor(s, 8);
  float lg = m + logf(s);
  if (lane < 16) {
    float4 o = {v.x - lg, v.y - lg, v.z - lg, v.w - lg};
    *(float4*)(&out[n * 64 + li * 4]) = o;
  }
}

extern "C" void kernel_launch(void* const* d_in, const int* in_sizes, int n_in,
                              void* d_out, int out_size, void* d_ws, size_t ws_size,
                              hipStream_t stream) {
  const float* x   = (const float*)d_in[0];
  const int*   ei  = (const int*)d_in[1];
  const float* W1l = (const float*)d_in[2];
  const float* b1  = (const float*)d_in[3];
  const float* W1r = (const float*)d_in[4];
  const float* W2l = (const float*)d_in[5];
  const float* b2  = (const float*)d_in[6];
  const float* W2r = (const float*)d_in[7];
  float* out = (float*)d_out;

  const int* src = ei;
  const int* dst = ei + N_EDGES;

  // workspace: bucket | deg | xh | yh | zh | wp
  u16* bucket = (u16*)d_ws;                                  // 5,120,000 B
  int* deg = (int*)(bucket + (size_t)N_NODES * CAP);         // 160,000 B
  u16* xh = (u16*)(deg + N_NODES);                           // 10,240,000 B
  u16* yh = xh + (size_t)N_NODES * FEATD;                    // 5,120,000 B
  u16* zh = yh + (size_t)N_NODES * EMB;                      // 5,120,000 B
  u16* wp = zh + (size_t)N_NODES * EMB;                      // 98,304 B

  hipMemsetAsync(deg, 0, N_NODES * sizeof(int), stream);
  prep_fill_kernel<<<2500 + 192 + 2500, 256, 0, stream>>>(
      x, W1l, W1r, W2l, W2r, src, dst, xh, wp, deg, bucket);
  gemm12_kernel<<<N_NODES / 64, 256, 0, stream>>>(xh, wp, b1, b2, deg, bucket, yh, zh);
  final_kernel<<<N_NODES / 4, 256, 0, stream>>>(yh, zh, deg, bucket, out);
}

// Round 9
// 185.348 us; speedup vs baseline: 1.1682x; 1.1682x over previous
//
#include <hip/hip_runtime.h>
#include <hip/hip_fp16.h>
#include <math.h>

#define N_NODES 40000
#define FEATD 128
#define EMB 64
#define N_EDGES 640000
#define CAP 64   // max in-degree bucket; Poisson(16) max over 40k nodes ~40

typedef unsigned short u16;
typedef __attribute__((ext_vector_type(8))) unsigned short u16x8;
typedef __attribute__((ext_vector_type(8))) _Float16 f16x8;
typedef __attribute__((ext_vector_type(4))) float f32x4;

__device__ __forceinline__ float h2f(u16 h) {
  __half hh;
  *(u16*)&hh = h;
  return __half2float(hh);
}
__device__ __forceinline__ u16 f2h(float f) {
  __half hh = __float2half(f);
  return *(u16*)&hh;
}

// ---- combined prep: x -> fp16 plane (blocks 0..2499), W -> fp16 plane (rest) ----
// wp layout (u16): w1l(16384) | w1r(16384) | w2l(8192) | w2r(8192)
__global__ __launch_bounds__(256) void prep_kernel(
    const float* __restrict__ x, const float* __restrict__ W1l,
    const float* __restrict__ W1r, const float* __restrict__ W2l,
    const float* __restrict__ W2r, u16* __restrict__ xh,
    u16* __restrict__ wp) {
  int bid = blockIdx.x;
  if (bid < 2500) {
    int i = bid * 256 + threadIdx.x;       // 8 elems each, covers 40000*128
    float4 v0 = *(const float4*)(&x[i * 8]);
    float4 v1 = *(const float4*)(&x[i * 8 + 4]);
    u16x8 o;
    o[0] = f2h(v0.x); o[1] = f2h(v0.y); o[2] = f2h(v0.z); o[3] = f2h(v0.w);
    o[4] = f2h(v1.x); o[5] = f2h(v1.y); o[6] = f2h(v1.z); o[7] = f2h(v1.w);
    *(u16x8*)(&xh[i * 8]) = o;
  } else {
    int i = (bid - 2500) * 256 + threadIdx.x;   // [0, 49152)
    const float* srcp;
    int off;
    if (i < 16384)      { srcp = W1l; off = i; }
    else if (i < 32768) { srcp = W1r; off = i - 16384; }
    else if (i < 40960) { srcp = W2l; off = i - 32768; }
    else                { srcp = W2r; off = i - 40960; }
    wp[i] = f2h(srcp[off]);
  }
}

// ---- CSR-bucket fill: 4 edges/thread -> 4 atomics + 4 stores in flight ----
__global__ __launch_bounds__(256) void fill_kernel(
    const int* __restrict__ src, const int* __restrict__ dst,
    int* __restrict__ deg, u16* __restrict__ bucket) {
  int t = blockIdx.x * 256 + threadIdx.x;   // [0, 160000)
  int4 s4 = *(const int4*)(&src[t * 4]);
  int4 d4 = *(const int4*)(&dst[t * 4]);
  int p0 = atomicAdd(&deg[d4.x], 1);
  int p1 = atomicAdd(&deg[d4.y], 1);
  int p2 = atomicAdd(&deg[d4.z], 1);
  int p3 = atomicAdd(&deg[d4.w], 1);
  if (p0 < CAP) bucket[d4.x * CAP + p0] = (u16)s4.x;
  if (p1 < CAP) bucket[d4.y * CAP + p1] = (u16)s4.y;
  if (p2 < CAP) bucket[d4.z * CAP + p2] = (u16)s4.z;
  if (p3 < CAP) bucket[d4.w * CAP + p3] = (u16)s4.w;
}

// ---- gather-mean over 128 fp16 feats: wave/node, 4 groups, 2 loads in flight ----
__global__ __launch_bounds__(256) void gather_mean_f16(
    const u16* __restrict__ xh, const int* __restrict__ deg,
    const u16* __restrict__ bucket, u16* __restrict__ aggh) {
  int n = blockIdx.x * 4 + (threadIdx.x >> 6);
  int lane = threadIdx.x & 63;
  int g = lane >> 4;
  int li = lane & 15;
  int dgf = deg[n];
  int dg = dgf < CAP ? dgf : CAP;
  float inv = 1.0f / fmaxf((float)dgf, 1.0f);
  const u16* bk = bucket + n * CAP;
  float acc0[8], acc1[8];
#pragma unroll
  for (int i = 0; i < 8; i++) { acc0[i] = 0.f; acc1[i] = 0.f; }
  int d = g;
  for (; d + 4 < dg; d += 8) {
    u16x8 v0 = *(const u16x8*)(&xh[(int)bk[d] * 128 + li * 8]);
    u16x8 v1 = *(const u16x8*)(&xh[(int)bk[d + 4] * 128 + li * 8]);
#pragma unroll
    for (int i = 0; i < 8; i++) { acc0[i] += h2f(v0[i]); acc1[i] += h2f(v1[i]); }
  }
  if (d < dg) {
    u16x8 v0 = *(const u16x8*)(&xh[(int)bk[d] * 128 + li * 8]);
#pragma unroll
    for (int i = 0; i < 8; i++) acc0[i] += h2f(v0[i]);
  }
#pragma unroll
  for (int i = 0; i < 8; i++) {
    acc0[i] += acc1[i];
    acc0[i] += __shfl_xor(acc0[i], 16);
    acc0[i] += __shfl_xor(acc0[i], 32);
  }
  if (g == 0) {
    u16x8 o;
#pragma unroll
    for (int i = 0; i < 8; i++) o[i] = f2h(acc0[i] * inv);
    *(u16x8*)(&aggh[n * 128 + li * 8]) = o;
  }
}

// ---- fused MFMA GEMM, both layers, native f16 MFMA (R7 structure) ----
__global__ __launch_bounds__(256) void gemm12_kernel(
    const u16* __restrict__ AggH, const u16* __restrict__ XH,
    const u16* __restrict__ wp, const float* __restrict__ b1v,
    const float* __restrict__ b2v, u16* __restrict__ Yh,
    float* __restrict__ Z) {
  const u16* w1l = wp;
  const u16* w1r = wp + 16384;
  const u16* w2l = wp + 32768;
  const u16* w2r = wp + 40960;

  __shared__ __align__(16) union {
    struct {                                   // 55296 B
      u16 wl[128][72], wr[128][72];
      u16 a[64][72], x[64][72];
    } p1;
    struct {                                   // 52224 B
      u16 h[64][136];
      u16 w2l[64][136], w2r[64][136];
    } p2;
  } L;

  const int tid = threadIdx.x;
  const int wv = tid >> 6;
  const int lane = tid & 63;
  const int li = lane & 15;
  const int q = lane >> 4;
  const int nbase = blockIdx.x * 64;

  f32x4 acc1[8];
#pragma unroll
  for (int jt = 0; jt < 8; jt++) acc1[jt] = (f32x4){0.f, 0.f, 0.f, 0.f};

  // ---------------- phase 1: two 64-k chunks ----------------
  for (int kb = 0; kb < 2; kb++) {
#pragma unroll
    for (int it = 0; it < 4; it++) {
      int idx = tid + 256 * it;        // [0,1024)
      int j = idx >> 3, c = idx & 7;   // j<128, c<8
      int go = j * 128 + kb * 64 + c * 8;
      *(u16x8*)(&L.p1.wl[j][c * 8]) = *(const u16x8*)(&w1l[go]);
      *(u16x8*)(&L.p1.wr[j][c * 8]) = *(const u16x8*)(&w1r[go]);
    }
#pragma unroll
    for (int it = 0; it < 2; it++) {
      int idx = tid + 256 * it;        // [0,512)
      int n = idx >> 3, c = idx & 7;
      int go = (nbase + n) * 128 + kb * 64 + c * 8;
      *(u16x8*)(&L.p1.a[n][c * 8]) = *(const u16x8*)(&AggH[go]);
      *(u16x8*)(&L.p1.x[n][c * 8]) = *(const u16x8*)(&XH[go]);
    }
    __syncthreads();
#pragma unroll
    for (int kk = 0; kk < 2; kk++) {
      f16x8 aF = *(const f16x8*)(&L.p1.a[wv * 16 + li][kk * 32 + q * 8]);
      f16x8 xF = *(const f16x8*)(&L.p1.x[wv * 16 + li][kk * 32 + q * 8]);
#pragma unroll
      for (int jt = 0; jt < 8; jt++) {
        f16x8 wlF = *(const f16x8*)(&L.p1.wl[jt * 16 + li][kk * 32 + q * 8]);
        f16x8 wrF = *(const f16x8*)(&L.p1.wr[jt * 16 + li][kk * 32 + q * 8]);
        acc1[jt] = __builtin_amdgcn_mfma_f32_16x16x32_f16(aF, wlF, acc1[jt], 0, 0, 0);
        acc1[jt] = __builtin_amdgcn_mfma_f32_16x16x32_f16(xF, wrF, acc1[jt], 0, 0, 0);
      }
    }
    __syncthreads();
  }

  // epilogue 1: bias + elu, h -> LDS fp16 (C/D: row = q*4+reg)
#pragma unroll
  for (int jt = 0; jt < 8; jt++) {
    int j = jt * 16 + li;
    float bb = b1v[j];
#pragma unroll
    for (int r = 0; r < 4; r++) {
      float v = acc1[jt][r] + bb;
      v = v > 0.f ? v : expm1f(v);
      L.p2.h[wv * 16 + q * 4 + r][j] = f2h(v);
    }
  }
  // stage W2 once: [64 j2][128 k]
#pragma unroll
  for (int it = 0; it < 4; it++) {
    int idx = tid + 256 * it;          // [0,1024)
    int j = idx >> 4, c = idx & 15;    // j<64, c<16
    int go = j * 128 + c * 8;
    *(u16x8*)(&L.p2.w2l[j][c * 8]) = *(const u16x8*)(&w2l[go]);
    *(u16x8*)(&L.p2.w2r[j][c * 8]) = *(const u16x8*)(&w2r[go]);
  }
  __syncthreads();

  // ---------------- phase 2: single barrier, 4 k-chunks ----------------
  f32x4 accY[4], accZ[4];
#pragma unroll
  for (int mt = 0; mt < 4; mt++) {
    accY[mt] = (f32x4){0.f, 0.f, 0.f, 0.f};
    accZ[mt] = (f32x4){0.f, 0.f, 0.f, 0.f};
  }
#pragma unroll
  for (int kc = 0; kc < 4; kc++) {
    f16x8 blF = *(const f16x8*)(&L.p2.w2l[wv * 16 + li][kc * 32 + q * 8]);
    f16x8 brF = *(const f16x8*)(&L.p2.w2r[wv * 16 + li][kc * 32 + q * 8]);
#pragma unroll
    for (int mt = 0; mt < 4; mt++) {
      f16x8 hF = *(const f16x8*)(&L.p2.h[mt * 16 + li][kc * 32 + q * 8]);
      accY[mt] = __builtin_amdgcn_mfma_f32_16x16x32_f16(hF, blF, accY[mt], 0, 0, 0);
      accZ[mt] = __builtin_amdgcn_mfma_f32_16x16x32_f16(hF, brF, accZ[mt], 0, 0, 0);
    }
  }

  // epilogue 2: y -> fp16, z -> fp32
  {
    int j2 = wv * 16 + li;
    float bb = b2v[j2];
#pragma unroll
    for (int mt = 0; mt < 4; mt++) {
#pragma unroll
      for (int r = 0; r < 4; r++) {
        int node = nbase + mt * 16 + q * 4 + r;
        Yh[node * 64 + j2] = f2h(accY[mt][r]);
        Z[node * 64 + j2] = accZ[mt][r] + bb;
      }
    }
  }
}

// ---- final: out = log_softmax(z + mean_j y_j), y fp16, 2 loads in flight ----
__global__ __launch_bounds__(256) void final_kernel(
    const u16* __restrict__ Y, const float* __restrict__ Z,
    const int* __restrict__ deg, const u16* __restrict__ bucket,
    float* __restrict__ out) {
  int n = blockIdx.x * 4 + (threadIdx.x >> 6);
  int lane = threadIdx.x & 63;
  int g = lane >> 4;
  int li = lane & 15;
  int dgf = deg[n];
  int dg = dgf < CAP ? dgf : CAP;
  float inv = 1.0f / fmaxf((float)dgf, 1.0f);
  const u16* bk = bucket + n * CAP;
  float4 acc = {0.f, 0.f, 0.f, 0.f};
  float4 accB = {0.f, 0.f, 0.f, 0.f};
  int d = g;
  for (; d + 4 < dg; d += 8) {
    ushort4 v0 = *(const ushort4*)(&Y[(int)bk[d] * 64 + li * 4]);
    ushort4 v1 = *(const ushort4*)(&Y[(int)bk[d + 4] * 64 + li * 4]);
    acc.x += h2f(v0.x); acc.y += h2f(v0.y); acc.z += h2f(v0.z); acc.w += h2f(v0.w);
    accB.x += h2f(v1.x); accB.y += h2f(v1.y); accB.z += h2f(v1.z); accB.w += h2f(v1.w);
  }
  if (d < dg) {
    ushort4 v0 = *(const ushort4*)(&Y[(int)bk[d] * 64 + li * 4]);
    acc.x += h2f(v0.x); acc.y += h2f(v0.y); acc.z += h2f(v0.z); acc.w += h2f(v0.w);
  }
  acc.x += accB.x; acc.y += accB.y; acc.z += accB.z; acc.w += accB.w;
  acc.x += __shfl_xor(acc.x, 16); acc.y += __shfl_xor(acc.y, 16);
  acc.z += __shfl_xor(acc.z, 16); acc.w += __shfl_xor(acc.w, 16);
  acc.x += __shfl_xor(acc.x, 32); acc.y += __shfl_xor(acc.y, 32);
  acc.z += __shfl_xor(acc.z, 32); acc.w += __shfl_xor(acc.w, 32);
  float4 zb = *(const float4*)(&Z[n * 64 + li * 4]);
  float4 v;
  v.x = zb.x + acc.x * inv; v.y = zb.y + acc.y * inv;
  v.z = zb.z + acc.z * inv; v.w = zb.w + acc.w * inv;
  float m = fmaxf(fmaxf(v.x, v.y), fmaxf(v.z, v.w));
  m = fmaxf(m, __shfl_xor(m, 1)); m = fmaxf(m, __shfl_xor(m, 2));
  m = fmaxf(m, __shfl_xor(m, 4)); m = fmaxf(m, __shfl_xor(m, 8));
  float s = __expf(v.x - m) + __expf(v.y - m) + __expf(v.z - m) + __expf(v.w - m);
  s += __shfl_xor(s, 1); s += __shfl_xor(s, 2);
  s += __shfl_xor(s, 4); s += __shfl_xor(s, 8);
  float lg = m + logf(s);
  if (lane < 16) {
    float4 o = {v.x - lg, v.y - lg, v.z - lg, v.w - lg};
    *(float4*)(&out[n * 64 + li * 4]) = o;
  }
}

extern "C" void kernel_launch(void* const* d_in, const int* in_sizes, int n_in,
                              void* d_out, int out_size, void* d_ws, size_t ws_size,
                              hipStream_t stream) {
  const float* x   = (const float*)d_in[0];
  const int*   ei  = (const int*)d_in[1];
  const float* W1l = (const float*)d_in[2];
  const float* b1  = (const float*)d_in[3];
  const float* W1r = (const float*)d_in[4];
  const float* W2l = (const float*)d_in[5];
  const float* b2  = (const float*)d_in[6];
  const float* W2r = (const float*)d_in[7];
  float* out = (float*)d_out;

  const int* src = ei;
  const int* dst = ei + N_EDGES;

  // workspace: bucket | deg | xh | aggh | yh | z | wp(fp16)
  u16* bucket = (u16*)d_ws;                                  // 5,120,000 B
  int* deg = (int*)(bucket + (size_t)N_NODES * CAP);         // 160,000 B
  u16* xh = (u16*)(deg + N_NODES);                           // 10,240,000 B
  u16* aggh = xh + (size_t)N_NODES * FEATD;                  // 10,240,000 B
  u16* yh = aggh + (size_t)N_NODES * FEATD;                  // 5,120,000 B
  float* z = (float*)(yh + (size_t)N_NODES * EMB);           // 10,240,000 B
  u16* wp = (u16*)(z + (size_t)N_NODES * EMB);               // 98,304 B

  hipMemsetAsync(deg, 0, N_NODES * sizeof(int), stream);
  prep_kernel<<<2500 + 192, 256, 0, stream>>>(x, W1l, W1r, W2l, W2r, xh, wp);
  fill_kernel<<<N_EDGES / 4 / 256, 256, 0, stream>>>(src, dst, deg, bucket);

  gather_mean_f16<<<N_NODES / 4, 256, 0, stream>>>(xh, deg, bucket, aggh);
  gemm12_kernel<<<N_NODES / 64, 256, 0, stream>>>(aggh, xh, wp, b1, b2, yh, z);
  final_kernel<<<N_NODES / 4, 256, 0, stream>>>(yh, z, deg, bucket, out);
}